// Round 2
// baseline (3107.214 us; speedup 1.0000x reference)
//
#include <hip/hip_runtime.h>

// B=1024, T=64, D=256, H=256, C=96, num_steps = batch_max_length+1 = 26.
constexpr int B  = 1024;
constexpr int T  = 64;
constexpr int D  = 256;
constexpr int H  = 256;
constexpr int C  = 96;
constexpr int NS = 26;
constexpr int G  = 4 * H;    // 1024 gate columns (i,f,g,o)

__device__ __forceinline__ float fsig(float x) {
    return 1.0f / (1.0f + __expf(-x));
}
__device__ __forceinline__ float ftanh(float x) {
    x = fminf(15.0f, fmaxf(-15.0f, x));
    float e = __expf(2.0f * x);
    return (e - 1.0f) / (e + 1.0f);
}

// ---------------------------------------------------------------------------
// proj[bt][h] = sum_d batch_H[bt][d] * Wi2h[d][h]  (one-time, 65536x256x256)
__global__ __launch_bounds__(256) void proj_kernel(
        const float* __restrict__ bH, const float* __restrict__ Wi2h,
        float* __restrict__ proj) {
    const int row0 = blockIdx.x * 8;
    const int j = threadIdx.x;
    float acc[8];
#pragma unroll
    for (int r = 0; r < 8; ++r) acc[r] = 0.0f;
    for (int k = 0; k < D; k += 4) {
        const float w0 = Wi2h[(k + 0) * H + j];
        const float w1 = Wi2h[(k + 1) * H + j];
        const float w2 = Wi2h[(k + 2) * H + j];
        const float w3 = Wi2h[(k + 3) * H + j];
#pragma unroll
        for (int r = 0; r < 8; ++r) {
            float4 x = *reinterpret_cast<const float4*>(&bH[(size_t)(row0 + r) * D + k]);
            acc[r] = fmaf(x.x, w0, acc[r]);
            acc[r] = fmaf(x.y, w1, acc[r]);
            acc[r] = fmaf(x.z, w2, acc[r]);
            acc[r] = fmaf(x.w, w3, acc[r]);
        }
    }
#pragma unroll
    for (int r = 0; r < 8; ++r) proj[(size_t)(row0 + r) * H + j] = acc[r];
}

// ---------------------------------------------------------------------------
// h0 = 0, c = 0, hp = bh2h  (step-0 hp is 0 @ Wh2h + bh2h = bh2h)
__global__ __launch_bounds__(256) void init_kernel(
        const float* __restrict__ bh2h, float* __restrict__ h0,
        float* __restrict__ c, float* __restrict__ hp) {
    const int i = blockIdx.x * 256 + threadIdx.x;
    h0[i] = 0.0f;
    c[i] = 0.0f;
    hp[i] = bh2h[threadIdx.x];
}

// ---------------------------------------------------------------------------
// Attention for one step. One block per batch row (grid=1024, 256 thr).
//   e[t] = sum_h tanh(proj[b,t,h] + hp[b,h]) * w_score[h]
//   alpha = softmax_t(e); context[b,d] = sum_t alpha[t] * batch_H[b,t,d]
__global__ __launch_bounds__(256) void attn_kernel(
        const float* __restrict__ proj, const float* __restrict__ bH,
        const float* __restrict__ hp, const float* __restrict__ w_score,
        float* __restrict__ context) {
    __shared__ float hp_s[H];
    __shared__ float ws_s[H];
    __shared__ float alpha_s[T];
    const int b = blockIdx.x, tid = threadIdx.x;
    hp_s[tid] = hp[b * H + tid];
    ws_s[tid] = w_score[tid];
    __syncthreads();

    const int wave = tid >> 6, lane = tid & 63;
    const float* pb = proj + (size_t)b * T * H;
    const float4 hv = *reinterpret_cast<const float4*>(&hp_s[lane * 4]);
    const float4 wv = *reinterpret_cast<const float4*>(&ws_s[lane * 4]);

#pragma unroll 4
    for (int i = 0; i < 16; ++i) {
        const int t = wave * 16 + i;
        float4 p = *reinterpret_cast<const float4*>(&pb[t * H + lane * 4]);
        float s = ftanh(p.x + hv.x) * wv.x + ftanh(p.y + hv.y) * wv.y +
                  ftanh(p.z + hv.z) * wv.z + ftanh(p.w + hv.w) * wv.w;
#pragma unroll
        for (int off = 32; off > 0; off >>= 1) s += __shfl_xor(s, off);
        if (lane == 0) alpha_s[t] = s;
    }
    __syncthreads();

    if (wave == 0) {  // 64 lanes == 64 timesteps
        float v = alpha_s[lane];
        float m = v;
#pragma unroll
        for (int off = 32; off > 0; off >>= 1) m = fmaxf(m, __shfl_xor(m, off));
        float p = __expf(v - m);
        float sum = p;
#pragma unroll
        for (int off = 32; off > 0; off >>= 1) sum += __shfl_xor(sum, off);
        alpha_s[lane] = p / sum;
    }
    __syncthreads();

    const float* xb = bH + (size_t)b * T * D;
    float acc0 = 0.0f, acc1 = 0.0f;
#pragma unroll 8
    for (int t = 0; t < T; t += 2) {
        acc0 = fmaf(alpha_s[t], xb[t * D + tid], acc0);
        acc1 = fmaf(alpha_s[t + 1], xb[(t + 1) * D + tid], acc1);
    }
    context[b * D + tid] = acc0 + acc1;
}

// ---------------------------------------------------------------------------
// Col-tiled fused LSTM step.
// Block: 256 thr = 4 row-groups x 64 h-cols. Tile: 16 rows x 64 h-cols
// (x4 gates). Grid: (B/16, H/64) = (64, 4). Per-block weight read: 512 KB
// -> 128 MB/step total (vs 576 MB untiled).
// h is double-buffered across steps (hprev read-only here) to avoid the
// cross-block race col-tiling would otherwise create.
__device__ __forceinline__ void gemm_tile(const float* __restrict__ X,
                                          const float* __restrict__ W,
                                          int rbase, int j, float a0[4],
                                          float a1[4], float a2[4], float a3[4]) {
    for (int k = 0; k < 256; k += 8) {
        float xr[4][8];
#pragma unroll
        for (int r = 0; r < 4; ++r) {
            float4 u = *reinterpret_cast<const float4*>(&X[(rbase + r) * 256 + k]);
            float4 v = *reinterpret_cast<const float4*>(&X[(rbase + r) * 256 + k + 4]);
            xr[r][0] = u.x; xr[r][1] = u.y; xr[r][2] = u.z; xr[r][3] = u.w;
            xr[r][4] = v.x; xr[r][5] = v.y; xr[r][6] = v.z; xr[r][7] = v.w;
        }
#pragma unroll
        for (int kk = 0; kk < 8; ++kk) {
            const float* wr = W + (size_t)(k + kk) * G + j;
            const float w0 = wr[0];
            const float w1 = wr[H];
            const float w2 = wr[2 * H];
            const float w3 = wr[3 * H];
#pragma unroll
            for (int r = 0; r < 4; ++r) {
                const float x = xr[r][kk];
                a0[r] = fmaf(x, w0, a0[r]);
                a1[r] = fmaf(x, w1, a1[r]);
                a2[r] = fmaf(x, w2, a2[r]);
                a3[r] = fmaf(x, w3, a3[r]);
            }
        }
    }
}

__global__ __launch_bounds__(256) void lstm_kernel(
        const float* __restrict__ ctx, const float* __restrict__ hprev,
        const float* __restrict__ Wx, const float* __restrict__ Wh,
        const float* __restrict__ b_lstm, const int* __restrict__ text,
        float* __restrict__ hnew, float* __restrict__ c,
        float* __restrict__ hiddens, int step) {
    const int rbase = blockIdx.x * 16 + (threadIdx.x >> 6) * 4;  // 4 rows/thread
    const int j = blockIdx.y * 64 + (threadIdx.x & 63);          // h-col

    float a0[4], a1[4], a2[4], a3[4];
    {
        const float b0 = b_lstm[j],         b1 = b_lstm[H + j];
        const float b2 = b_lstm[2 * H + j], b3 = b_lstm[3 * H + j];
#pragma unroll
        for (int r = 0; r < 4; ++r) {
            const int ch = text[(rbase + r) * NS + step];
            const float* wrow = Wx + (size_t)(D + ch) * G;  // one-hot row of Wx
            a0[r] = b0 + wrow[j];
            a1[r] = b1 + wrow[H + j];
            a2[r] = b2 + wrow[2 * H + j];
            a3[r] = b3 + wrow[3 * H + j];
        }
    }
    gemm_tile(ctx,   Wx, rbase, j, a0, a1, a2, a3);  // context part (Wx rows 0..D-1)
    gemm_tile(hprev, Wh, rbase, j, a0, a1, a2, a3);  // recurrent part

#pragma unroll
    for (int r = 0; r < 4; ++r) {
        const int idx = (rbase + r) * H + j;
        const float cv = fsig(a1[r]) * c[idx] + fsig(a0[r]) * ftanh(a2[r]);
        c[idx] = cv;
        const float hv = fsig(a3[r]) * ftanh(cv);
        hnew[idx] = hv;
        hiddens[((size_t)(rbase + r) * NS + step) * H + j] = hv;
    }
}

// ---------------------------------------------------------------------------
// hp = h_new @ Wh2h + bh2h   (B x 256 @ 256 x 256; 8 rows/block, 128 blocks)
__global__ __launch_bounds__(256) void hp_kernel(
        const float* __restrict__ h, const float* __restrict__ Wh2h,
        const float* __restrict__ bh2h, float* __restrict__ hp) {
    const int row0 = blockIdx.x * 8;
    const int j = threadIdx.x;
    float acc[8];
    const float bb = bh2h[j];
#pragma unroll
    for (int r = 0; r < 8; ++r) acc[r] = bb;
    for (int k = 0; k < H; k += 4) {
        const float w0 = Wh2h[(k + 0) * H + j];
        const float w1 = Wh2h[(k + 1) * H + j];
        const float w2 = Wh2h[(k + 2) * H + j];
        const float w3 = Wh2h[(k + 3) * H + j];
#pragma unroll
        for (int r = 0; r < 8; ++r) {
            float4 x = *reinterpret_cast<const float4*>(&h[(size_t)(row0 + r) * H + k]);
            acc[r] = fmaf(x.x, w0, acc[r]);
            acc[r] = fmaf(x.y, w1, acc[r]);
            acc[r] = fmaf(x.z, w2, acc[r]);
            acc[r] = fmaf(x.w, w3, acc[r]);
        }
    }
#pragma unroll
    for (int r = 0; r < 8; ++r) hp[(row0 + r) * H + j] = acc[r];
}

// ---------------------------------------------------------------------------
// probs[bt][cls] = hiddens[bt][:] @ Wg + bg
__global__ __launch_bounds__(192) void gen_kernel(
        const float* __restrict__ hiddens, const float* __restrict__ Wg,
        const float* __restrict__ bg, float* __restrict__ out) {
    const int row0 = blockIdx.x * 16 + (threadIdx.x / 96) * 8;
    const int cc = threadIdx.x % 96;
    float acc[8];
    const float bias = bg[cc];
#pragma unroll
    for (int r = 0; r < 8; ++r) acc[r] = bias;
    for (int k = 0; k < H; k += 4) {
        const float w0 = Wg[(k + 0) * C + cc];
        const float w1 = Wg[(k + 1) * C + cc];
        const float w2 = Wg[(k + 2) * C + cc];
        const float w3 = Wg[(k + 3) * C + cc];
#pragma unroll
        for (int r = 0; r < 8; ++r) {
            float4 x = *reinterpret_cast<const float4*>(&hiddens[(size_t)(row0 + r) * H + k]);
            acc[r] = fmaf(x.x, w0, acc[r]);
            acc[r] = fmaf(x.y, w1, acc[r]);
            acc[r] = fmaf(x.z, w2, acc[r]);
            acc[r] = fmaf(x.w, w3, acc[r]);
        }
    }
#pragma unroll
    for (int r = 0; r < 8; ++r) out[(size_t)(row0 + r) * C + cc] = acc[r];
}

// ---------------------------------------------------------------------------
extern "C" void kernel_launch(void* const* d_in, const int* in_sizes, int n_in,
                              void* d_out, int out_size, void* d_ws, size_t ws_size,
                              hipStream_t stream) {
    const float* batch_H = (const float*)d_in[0];
    const int*   text    = (const int*)d_in[1];
    // d_in[2] = batch_max_length (scalar) -> NS hardcoded (out_size/B/C = 26)
    const float* Wi2h    = (const float*)d_in[3];
    const float* Wh2h    = (const float*)d_in[4];
    const float* bh2h    = (const float*)d_in[5];
    const float* w_score = (const float*)d_in[6];
    const float* Wx      = (const float*)d_in[7];
    const float* Wh      = (const float*)d_in[8];
    const float* b_lstm  = (const float*)d_in[9];
    const float* Wg      = (const float*)d_in[10];
    const float* bg      = (const float*)d_in[11];
    float* out = (float*)d_out;

    // workspace (floats): proj | h0 | h1 | c | hp | context | hiddens (~100 MB)
    float* ws      = (float*)d_ws;
    float* proj    = ws;                          // B*T*H
    float* h0      = proj + (size_t)B * T * H;    // B*H
    float* h1      = h0 + B * H;                  // B*H
    float* c       = h1 + B * H;                  // B*H
    float* hp      = c + B * H;                   // B*H
    float* context = hp + B * H;                  // B*D
    float* hiddens = context + B * D;             // B*NS*H

    proj_kernel<<<B * T / 8, 256, 0, stream>>>(batch_H, Wi2h, proj);
    init_kernel<<<B * H / 256, 256, 0, stream>>>(bh2h, h0, c, hp);

    float* hbuf[2] = {h0, h1};
    for (int t = 0; t < NS; ++t) {
        float* hprev = hbuf[t & 1];
        float* hnew  = hbuf[(t + 1) & 1];
        attn_kernel<<<B, 256, 0, stream>>>(proj, batch_H, hp, w_score, context);
        lstm_kernel<<<dim3(B / 16, H / 64), 256, 0, stream>>>(
            context, hprev, Wx, Wh, b_lstm, text, hnew, c, hiddens, t);
        hp_kernel<<<B / 8, 256, 0, stream>>>(hnew, Wh2h, bh2h, hp);
    }
    gen_kernel<<<B * NS / 16, 192, 0, stream>>>(hiddens, Wg, bg, out);
}

// Round 3
// 2725.267 us; speedup vs baseline: 1.1402x; 1.1402x over previous
//
#include <hip/hip_runtime.h>

// B=1024, T=64, D=256, H=256, C=96, num_steps = batch_max_length+1 = 26.
constexpr int B  = 1024;
constexpr int T  = 64;
constexpr int D  = 256;
constexpr int H  = 256;
constexpr int C  = 96;
constexpr int NS = 26;
constexpr int G  = 4 * H;    // 1024 gate columns (i,f,g,o)

__device__ __forceinline__ float fsig(float x) {
    return 1.0f / (1.0f + __expf(-x));
}
__device__ __forceinline__ float ftanh(float x) {
    x = fminf(15.0f, fmaxf(-15.0f, x));
    float e = __expf(2.0f * x);
    return (e - 1.0f) / (e + 1.0f);
}

// ---------------------------------------------------------------------------
// proj[bt][h] = sum_d batch_H[bt][d] * Wi2h[d][h]  (one-time, 65536x256x256)
// v2: 16 rows/block staged in LDS; x reads are broadcast ds_read_b128 (cheap),
// W streams coalesced from L2. 4096 blocks, 16KB LDS -> 8 blocks/CU.
__global__ __launch_bounds__(256) void proj_kernel(
        const float* __restrict__ bH, const float* __restrict__ Wi2h,
        float* __restrict__ proj) {
    __shared__ float xsm[16 * 256];
    const int row0 = blockIdx.x * 16;
    const int j = threadIdx.x;

    const float4* src = reinterpret_cast<const float4*>(bH + (size_t)row0 * D);
    float4* dst = reinterpret_cast<float4*>(xsm);
#pragma unroll
    for (int i = 0; i < 4; ++i) dst[j + 256 * i] = src[j + 256 * i];
    __syncthreads();

    float acc[16];
#pragma unroll
    for (int r = 0; r < 16; ++r) acc[r] = 0.0f;

    for (int k = 0; k < D; k += 4) {
        const float w0 = Wi2h[(k + 0) * H + j];
        const float w1 = Wi2h[(k + 1) * H + j];
        const float w2 = Wi2h[(k + 2) * H + j];
        const float w3 = Wi2h[(k + 3) * H + j];
#pragma unroll
        for (int r = 0; r < 16; ++r) {
            float4 x = *reinterpret_cast<const float4*>(&xsm[r * 256 + k]);
            acc[r] = fmaf(x.x, w0, acc[r]);
            acc[r] = fmaf(x.y, w1, acc[r]);
            acc[r] = fmaf(x.z, w2, acc[r]);
            acc[r] = fmaf(x.w, w3, acc[r]);
        }
    }
#pragma unroll
    for (int r = 0; r < 16; ++r) proj[(size_t)(row0 + r) * H + j] = acc[r];
}

// ---------------------------------------------------------------------------
__global__ __launch_bounds__(256) void init_kernel(
        const float* __restrict__ bh2h, float* __restrict__ h0,
        float* __restrict__ c, float* __restrict__ hp) {
    const int i = blockIdx.x * 256 + threadIdx.x;
    h0[i] = 0.0f;
    c[i] = 0.0f;
    hp[i] = bh2h[threadIdx.x];
}

// ---------------------------------------------------------------------------
// Attention for one step. One block per batch row (grid=1024, 256 thr).
__global__ __launch_bounds__(256) void attn_kernel(
        const float* __restrict__ proj, const float* __restrict__ bH,
        const float* __restrict__ hp, const float* __restrict__ w_score,
        float* __restrict__ context) {
    __shared__ float hp_s[H];
    __shared__ float ws_s[H];
    __shared__ float alpha_s[T];
    const int b = blockIdx.x, tid = threadIdx.x;
    hp_s[tid] = hp[b * H + tid];
    ws_s[tid] = w_score[tid];
    __syncthreads();

    const int wave = tid >> 6, lane = tid & 63;
    const float* pb = proj + (size_t)b * T * H;
    const float4 hv = *reinterpret_cast<const float4*>(&hp_s[lane * 4]);
    const float4 wv = *reinterpret_cast<const float4*>(&ws_s[lane * 4]);

#pragma unroll 4
    for (int i = 0; i < 16; ++i) {
        const int t = wave * 16 + i;
        float4 p = *reinterpret_cast<const float4*>(&pb[t * H + lane * 4]);
        float s = ftanh(p.x + hv.x) * wv.x + ftanh(p.y + hv.y) * wv.y +
                  ftanh(p.z + hv.z) * wv.z + ftanh(p.w + hv.w) * wv.w;
#pragma unroll
        for (int off = 32; off > 0; off >>= 1) s += __shfl_xor(s, off);
        if (lane == 0) alpha_s[t] = s;
    }
    __syncthreads();

    if (wave == 0) {
        float v = alpha_s[lane];
        float m = v;
#pragma unroll
        for (int off = 32; off > 0; off >>= 1) m = fmaxf(m, __shfl_xor(m, off));
        float p = __expf(v - m);
        float sum = p;
#pragma unroll
        for (int off = 32; off > 0; off >>= 1) sum += __shfl_xor(sum, off);
        alpha_s[lane] = p / sum;
    }
    __syncthreads();

    const float* xb = bH + (size_t)b * T * D;
    float acc0 = 0.0f, acc1 = 0.0f;
#pragma unroll 8
    for (int t = 0; t < T; t += 2) {
        acc0 = fmaf(alpha_s[t], xb[t * D + tid], acc0);
        acc1 = fmaf(alpha_s[t + 1], xb[(t + 1) * D + tid], acc1);
    }
    context[b * D + tid] = acc0 + acc1;
}

// ---------------------------------------------------------------------------
// LSTM step v2. Block: 256 thr = 4 waves (one per GATE) x 64 lanes x 2 h-cols.
// Tile: 8 batch rows x 128 h-cols x 4 gates. Grid (B/8, H/128) = (128, 2)
// = 512 blocks -> 2 waves/SIMD. ctx/h rows staged in LDS (broadcast reads);
// gates exchanged via LDS for the pointwise. h double-buffered across steps.
__global__ __launch_bounds__(256) void lstm_kernel(
        const float* __restrict__ ctx, const float* __restrict__ hprev,
        const float* __restrict__ Wx, const float* __restrict__ Wh,
        const float* __restrict__ b_lstm, const int* __restrict__ text,
        float* __restrict__ hnew, float* __restrict__ c,
        float* __restrict__ hiddens, int step) {
    __shared__ float smem[4096];          // xs[8][256] | hs[8][256], then gs
    float* xs = smem;
    float* hs = smem + 2048;

    const int row0 = blockIdx.x * 8;
    const int cg   = blockIdx.y;          // col-group (128 h-cols)
    const int tid  = threadIdx.x;
    const int g    = tid >> 6;            // gate index = wave
    const int lane = tid & 63;
    const int c0   = cg * 128 + lane * 2; // h-col pair

    // stage 8 ctx rows + 8 h rows (each 8KB) coalesced
    {
        const float4* sx = reinterpret_cast<const float4*>(ctx + (size_t)row0 * H);
        const float4* sh = reinterpret_cast<const float4*>(hprev + (size_t)row0 * H);
        float4* dx = reinterpret_cast<float4*>(xs);
        float4* dh = reinterpret_cast<float4*>(hs);
        dx[tid] = sx[tid];
        dx[tid + 256] = sx[tid + 256];
        dh[tid] = sh[tid];
        dh[tid + 256] = sh[tid + 256];
    }

    float acc[8][2];
    {
        const float2 bb = *reinterpret_cast<const float2*>(&b_lstm[g * H + c0]);
#pragma unroll
        for (int r = 0; r < 8; ++r) {
            const int ch = text[(row0 + r) * NS + step];
            const float2 oh =
                *reinterpret_cast<const float2*>(&Wx[(size_t)(D + ch) * G + g * H + c0]);
            acc[r][0] = bb.x + oh.x;
            acc[r][1] = bb.y + oh.y;
        }
    }
    __syncthreads();

    // gates += ctx @ Wx[0:D] + hprev @ Wh
    const float* WbX = Wx + g * H + c0;
    const float* WbH = Wh + g * H + c0;
    for (int k = 0; k < D; k += 4) {
        const float2 w0 = *reinterpret_cast<const float2*>(&WbX[(size_t)(k + 0) * G]);
        const float2 w1 = *reinterpret_cast<const float2*>(&WbX[(size_t)(k + 1) * G]);
        const float2 w2 = *reinterpret_cast<const float2*>(&WbX[(size_t)(k + 2) * G]);
        const float2 w3 = *reinterpret_cast<const float2*>(&WbX[(size_t)(k + 3) * G]);
#pragma unroll
        for (int r = 0; r < 8; ++r) {
            float4 x = *reinterpret_cast<const float4*>(&xs[r * 256 + k]);
            acc[r][0] = fmaf(x.x, w0.x, acc[r][0]);
            acc[r][1] = fmaf(x.x, w0.y, acc[r][1]);
            acc[r][0] = fmaf(x.y, w1.x, acc[r][0]);
            acc[r][1] = fmaf(x.y, w1.y, acc[r][1]);
            acc[r][0] = fmaf(x.z, w2.x, acc[r][0]);
            acc[r][1] = fmaf(x.z, w2.y, acc[r][1]);
            acc[r][0] = fmaf(x.w, w3.x, acc[r][0]);
            acc[r][1] = fmaf(x.w, w3.y, acc[r][1]);
        }
    }
    for (int k = 0; k < H; k += 4) {
        const float2 w0 = *reinterpret_cast<const float2*>(&WbH[(size_t)(k + 0) * G]);
        const float2 w1 = *reinterpret_cast<const float2*>(&WbH[(size_t)(k + 1) * G]);
        const float2 w2 = *reinterpret_cast<const float2*>(&WbH[(size_t)(k + 2) * G]);
        const float2 w3 = *reinterpret_cast<const float2*>(&WbH[(size_t)(k + 3) * G]);
#pragma unroll
        for (int r = 0; r < 8; ++r) {
            float4 x = *reinterpret_cast<const float4*>(&hs[r * 256 + k]);
            acc[r][0] = fmaf(x.x, w0.x, acc[r][0]);
            acc[r][1] = fmaf(x.x, w0.y, acc[r][1]);
            acc[r][0] = fmaf(x.y, w1.x, acc[r][0]);
            acc[r][1] = fmaf(x.y, w1.y, acc[r][1]);
            acc[r][0] = fmaf(x.z, w2.x, acc[r][0]);
            acc[r][1] = fmaf(x.z, w2.y, acc[r][1]);
            acc[r][0] = fmaf(x.w, w3.x, acc[r][0]);
            acc[r][1] = fmaf(x.w, w3.y, acc[r][1]);
        }
    }
    __syncthreads();  // xs/hs reads done; reuse smem for gate exchange

    // gs[r][cl][gate], cl = local h-col 0..127
    float* gs = smem;
#pragma unroll
    for (int r = 0; r < 8; ++r) {
        gs[(r * 128 + lane * 2 + 0) * 4 + g] = acc[r][0];
        gs[(r * 128 + lane * 2 + 1) * 4 + g] = acc[r][1];
    }
    __syncthreads();

    // pointwise: 256 thr x 4 (row,col) pairs cover 8x128
#pragma unroll
    for (int p = 0; p < 4; ++p) {
        const int idx = tid + 256 * p;
        const int r = idx >> 7, cl = idx & 127;
        const int col = cg * 128 + cl;
        const float gi = gs[(r * 128 + cl) * 4 + 0];
        const float gf = gs[(r * 128 + cl) * 4 + 1];
        const float gc = gs[(r * 128 + cl) * 4 + 2];
        const float go = gs[(r * 128 + cl) * 4 + 3];
        const int cidx = (row0 + r) * H + col;
        const float cv = fsig(gf) * c[cidx] + fsig(gi) * ftanh(gc);
        c[cidx] = cv;
        const float hv = fsig(go) * ftanh(cv);
        hnew[cidx] = hv;
        hiddens[((size_t)(row0 + r) * NS + step) * H + col] = hv;
    }
}

// ---------------------------------------------------------------------------
// hp = h_new @ Wh2h + bh2h. v2: 4 rows/block -> 256 blocks, h rows in LDS.
__global__ __launch_bounds__(256) void hp_kernel(
        const float* __restrict__ h, const float* __restrict__ Wh2h,
        const float* __restrict__ bh2h, float* __restrict__ hp) {
    __shared__ float hsm[4 * 256];
    const int row0 = blockIdx.x * 4;
    const int j = threadIdx.x;
    reinterpret_cast<float4*>(hsm)[j] =
        reinterpret_cast<const float4*>(h + (size_t)row0 * H)[j];
    __syncthreads();

    float acc[4];
    const float bb = bh2h[j];
#pragma unroll
    for (int r = 0; r < 4; ++r) acc[r] = bb;
    for (int k = 0; k < H; k += 4) {
        const float w0 = Wh2h[(k + 0) * H + j];
        const float w1 = Wh2h[(k + 1) * H + j];
        const float w2 = Wh2h[(k + 2) * H + j];
        const float w3 = Wh2h[(k + 3) * H + j];
#pragma unroll
        for (int r = 0; r < 4; ++r) {
            float4 x = *reinterpret_cast<const float4*>(&hsm[r * 256 + k]);
            acc[r] = fmaf(x.x, w0, acc[r]);
            acc[r] = fmaf(x.y, w1, acc[r]);
            acc[r] = fmaf(x.z, w2, acc[r]);
            acc[r] = fmaf(x.w, w3, acc[r]);
        }
    }
#pragma unroll
    for (int r = 0; r < 4; ++r) hp[(row0 + r) * H + j] = acc[r];
}

// ---------------------------------------------------------------------------
// probs[bt][cls] = hiddens[bt][:] @ Wg + bg
__global__ __launch_bounds__(192) void gen_kernel(
        const float* __restrict__ hiddens, const float* __restrict__ Wg,
        const float* __restrict__ bg, float* __restrict__ out) {
    const int row0 = blockIdx.x * 16 + (threadIdx.x / 96) * 8;
    const int cc = threadIdx.x % 96;
    float acc[8];
    const float bias = bg[cc];
#pragma unroll
    for (int r = 0; r < 8; ++r) acc[r] = bias;
    for (int k = 0; k < H; k += 4) {
        const float w0 = Wg[(k + 0) * C + cc];
        const float w1 = Wg[(k + 1) * C + cc];
        const float w2 = Wg[(k + 2) * C + cc];
        const float w3 = Wg[(k + 3) * C + cc];
#pragma unroll
        for (int r = 0; r < 8; ++r) {
            float4 x = *reinterpret_cast<const float4*>(&hiddens[(size_t)(row0 + r) * H + k]);
            acc[r] = fmaf(x.x, w0, acc[r]);
            acc[r] = fmaf(x.y, w1, acc[r]);
            acc[r] = fmaf(x.z, w2, acc[r]);
            acc[r] = fmaf(x.w, w3, acc[r]);
        }
    }
#pragma unroll
    for (int r = 0; r < 8; ++r) out[(size_t)(row0 + r) * C + cc] = acc[r];
}

// ---------------------------------------------------------------------------
extern "C" void kernel_launch(void* const* d_in, const int* in_sizes, int n_in,
                              void* d_out, int out_size, void* d_ws, size_t ws_size,
                              hipStream_t stream) {
    const float* batch_H = (const float*)d_in[0];
    const int*   text    = (const int*)d_in[1];
    // d_in[2] = batch_max_length (scalar) -> NS hardcoded (out_size/B/C = 26)
    const float* Wi2h    = (const float*)d_in[3];
    const float* Wh2h    = (const float*)d_in[4];
    const float* bh2h    = (const float*)d_in[5];
    const float* w_score = (const float*)d_in[6];
    const float* Wx      = (const float*)d_in[7];
    const float* Wh      = (const float*)d_in[8];
    const float* b_lstm  = (const float*)d_in[9];
    const float* Wg      = (const float*)d_in[10];
    const float* bg      = (const float*)d_in[11];
    float* out = (float*)d_out;

    // workspace (floats): proj | h0 | h1 | c | hp | context | hiddens (~100 MB)
    float* ws      = (float*)d_ws;
    float* proj    = ws;                          // B*T*H
    float* h0      = proj + (size_t)B * T * H;    // B*H
    float* h1      = h0 + B * H;                  // B*H
    float* c       = h1 + B * H;                  // B*H
    float* hp      = c + B * H;                   // B*H
    float* context = hp + B * H;                  // B*D
    float* hiddens = context + B * D;             // B*NS*H

    proj_kernel<<<B * T / 16, 256, 0, stream>>>(batch_H, Wi2h, proj);
    init_kernel<<<B * H / 256, 256, 0, stream>>>(bh2h, h0, c, hp);

    float* hbuf[2] = {h0, h1};
    for (int t = 0; t < NS; ++t) {
        float* hprev = hbuf[t & 1];
        float* hnew  = hbuf[(t + 1) & 1];
        attn_kernel<<<B, 256, 0, stream>>>(proj, batch_H, hp, w_score, context);
        lstm_kernel<<<dim3(B / 8, H / 128), 256, 0, stream>>>(
            context, hprev, Wx, Wh, b_lstm, text, hnew, c, hiddens, t);
        hp_kernel<<<B / 4, 256, 0, stream>>>(hnew, Wh2h, bh2h, hp);
    }
    gen_kernel<<<B * NS / 16, 192, 0, stream>>>(hiddens, Wg, bg, out);
}

// Round 5
// 1476.907 us; speedup vs baseline: 2.1039x; 1.8453x over previous
//
#include <hip/hip_runtime.h>

// B=1024, T=64, D=256, H=256, C=96, num_steps = batch_max_length+1 = 26.
constexpr int B  = 1024;
constexpr int T  = 64;
constexpr int D  = 256;
constexpr int H  = 256;
constexpr int C  = 96;
constexpr int NS = 26;
constexpr int G  = 4 * H;    // 1024 gate columns (i,f,g,o)

__device__ __forceinline__ float fsig(float x) {
    // 1/(1+e^-x); rcp(inf)=0, rcp(1)=1 -> graceful at extremes
    return __builtin_amdgcn_rcpf(1.0f + __expf(-x));
}
__device__ __forceinline__ float ftanh(float x) {
    // 1 - 2/(e^{2x}+1); exp overflow -> rcp(inf)=0 -> 1; underflow -> -1
    float e = __expf(2.0f * x);
    return fmaf(-2.0f, __builtin_amdgcn_rcpf(e + 1.0f), 1.0f);
}

// ---------------------------------------------------------------------------
// proj[bt][h] = sum_d batch_H[bt][d] * Wi2h[d][h]  (one-time, 65536x256x256)
// v3: 32 rows/block in LDS; thread = (8 rows x 4 cols) so one ds_read_b128
// feeds 16 FMAs -> VALU-bound. 2048 blocks.
__global__ __launch_bounds__(256) void proj_kernel(
        const float* __restrict__ bH, const float* __restrict__ Wi2h,
        float* __restrict__ proj) {
    __shared__ float xs[32 * 256];
    const int row0 = blockIdx.x * 32;
    const int tid = threadIdx.x;

    const float4* src = reinterpret_cast<const float4*>(bH + (size_t)row0 * D);
    float4* dst = reinterpret_cast<float4*>(xs);
#pragma unroll
    for (int i = 0; i < 8; ++i) dst[tid + 256 * i] = src[tid + 256 * i];
    __syncthreads();

    const int wv = tid >> 6, lane = tid & 63;
    const int r0 = wv * 8;         // 8 rows per wave
    const int c0 = lane * 4;       // 4 cols per lane
    float4 acc[8];
#pragma unroll
    for (int r = 0; r < 8; ++r) acc[r] = make_float4(0.f, 0.f, 0.f, 0.f);

    for (int k = 0; k < D; k += 4) {
        const float4 w0 = *reinterpret_cast<const float4*>(&Wi2h[(k + 0) * H + c0]);
        const float4 w1 = *reinterpret_cast<const float4*>(&Wi2h[(k + 1) * H + c0]);
        const float4 w2 = *reinterpret_cast<const float4*>(&Wi2h[(k + 2) * H + c0]);
        const float4 w3 = *reinterpret_cast<const float4*>(&Wi2h[(k + 3) * H + c0]);
#pragma unroll
        for (int r = 0; r < 8; ++r) {
            const float4 x = *reinterpret_cast<const float4*>(&xs[(r0 + r) * 256 + k]);
            acc[r].x = fmaf(x.x, w0.x, fmaf(x.y, w1.x, fmaf(x.z, w2.x, fmaf(x.w, w3.x, acc[r].x))));
            acc[r].y = fmaf(x.x, w0.y, fmaf(x.y, w1.y, fmaf(x.z, w2.y, fmaf(x.w, w3.y, acc[r].y))));
            acc[r].z = fmaf(x.x, w0.z, fmaf(x.y, w1.z, fmaf(x.z, w2.z, fmaf(x.w, w3.z, acc[r].z))));
            acc[r].w = fmaf(x.x, w0.w, fmaf(x.y, w1.w, fmaf(x.z, w2.w, fmaf(x.w, w3.w, acc[r].w))));
        }
    }
#pragma unroll
    for (int r = 0; r < 8; ++r)
        *reinterpret_cast<float4*>(&proj[(size_t)(row0 + r0 + r) * H + c0]) = acc[r];
}

// ---------------------------------------------------------------------------
// Persistent decoder: grid 256 blocks x 512 thr; 4 batch rows per block;
// all 26 steps in-kernel. State (h, c, hp, ctx, gates) lives in LDS.
// Per step:
//   phase1: waves 0-3 attention (row = wave) || waves 4-7 gates = b + onehot + h@Wh
//   phase2: all 8 waves gates += ctx@Wx
//   phase3: pointwise LSTM cell -> h,c,hiddens;  then hp = h@Wh2h + bh2h
__global__ __launch_bounds__(512) void decoder_kernel(
        const float* __restrict__ proj, const float* __restrict__ bH,
        const int* __restrict__ text, const float* __restrict__ Wx,
        const float* __restrict__ Wh, const float* __restrict__ b_lstm,
        const float* __restrict__ Wh2h, const float* __restrict__ bh2h,
        const float* __restrict__ w_score, float* __restrict__ hiddens) {
    __shared__ float hp_s[4][256];
    __shared__ float h_s[4][256];
    __shared__ float c_s[4][256];
    __shared__ float ctx_s[4][256];
    __shared__ float gates[4][1024];
    __shared__ float alpha_s[4][64];
    __shared__ float ws_s[256];

    const int row0 = blockIdx.x * 4;
    const int tid = threadIdx.x;
    const int wv = tid >> 6, lane = tid & 63;

    for (int i = tid; i < 1024; i += 512) {
        const int r = i >> 8, j = i & 255;
        h_s[r][j] = 0.0f;
        c_s[r][j] = 0.0f;
        hp_s[r][j] = bh2h[j];
    }
    if (tid < 256) ws_s[tid] = w_score[tid];
    __syncthreads();

    for (int t = 0; t < NS; ++t) {
        if (wv < 4) {
            // ---------------- attention for row r = wv ----------------
            const int r = wv;
            const float* pb = proj + (size_t)(row0 + r) * T * H;
            const float4 hv = *reinterpret_cast<const float4*>(&hp_s[r][lane * 4]);
            const float4 wq = *reinterpret_cast<const float4*>(&ws_s[lane * 4]);
            // scores: 4 t's in flight for load/shfl ILP
            for (int tt = 0; tt < T; tt += 4) {
                float s[4];
#pragma unroll
                for (int q = 0; q < 4; ++q) {
                    const float4 p =
                        *reinterpret_cast<const float4*>(&pb[(tt + q) * H + lane * 4]);
                    s[q] = ftanh(p.x + hv.x) * wq.x + ftanh(p.y + hv.y) * wq.y +
                           ftanh(p.z + hv.z) * wq.z + ftanh(p.w + hv.w) * wq.w;
                }
#pragma unroll
                for (int off = 32; off > 0; off >>= 1) {
#pragma unroll
                    for (int q = 0; q < 4; ++q) s[q] += __shfl_xor(s[q], off);
                }
                if (lane == 0) {
#pragma unroll
                    for (int q = 0; q < 4; ++q) alpha_s[r][tt + q] = s[q];
                }
            }
            // softmax: 64 lanes = 64 timesteps (same-wave LDS ordering is safe)
            {
                const float v = alpha_s[r][lane];
                float m = v;
#pragma unroll
                for (int off = 32; off > 0; off >>= 1) m = fmaxf(m, __shfl_xor(m, off));
                const float p = __expf(v - m);
                float sum = p;
#pragma unroll
                for (int off = 32; off > 0; off >>= 1) sum += __shfl_xor(sum, off);
                alpha_s[r][lane] = p * __builtin_amdgcn_rcpf(sum);
            }
            // context: lane owns d = lane*4 .. +3
            {
                const float* xb = bH + (size_t)(row0 + r) * T * D;
                float4 cacc = make_float4(0.f, 0.f, 0.f, 0.f);
#pragma unroll 4
                for (int tt = 0; tt < T; ++tt) {
                    const float av = alpha_s[r][tt];
                    const float4 x =
                        *reinterpret_cast<const float4*>(&xb[tt * D + lane * 4]);
                    cacc.x = fmaf(av, x.x, cacc.x);
                    cacc.y = fmaf(av, x.y, cacc.y);
                    cacc.z = fmaf(av, x.z, cacc.z);
                    cacc.w = fmaf(av, x.w, cacc.w);
                }
                *reinterpret_cast<float4*>(&ctx_s[r][lane * 4]) = cacc;
            }
        } else {
            // ------------- gates partial: bias + onehot + h@Wh -------------
            // wave (wv-4) owns 256 gate-cols; lane owns 4 (float4)
            const int cw = (wv - 4) * 256 + lane * 4;
            float4 a0, a1, a2, a3;
            {
                const float4 bb = *reinterpret_cast<const float4*>(&b_lstm[cw]);
                const int ch0 = text[(row0 + 0) * NS + t];
                const int ch1 = text[(row0 + 1) * NS + t];
                const int ch2 = text[(row0 + 2) * NS + t];
                const int ch3 = text[(row0 + 3) * NS + t];
                const float4 o0 = *reinterpret_cast<const float4*>(&Wx[(size_t)(D + ch0) * G + cw]);
                const float4 o1 = *reinterpret_cast<const float4*>(&Wx[(size_t)(D + ch1) * G + cw]);
                const float4 o2 = *reinterpret_cast<const float4*>(&Wx[(size_t)(D + ch2) * G + cw]);
                const float4 o3 = *reinterpret_cast<const float4*>(&Wx[(size_t)(D + ch3) * G + cw]);
                a0 = make_float4(bb.x + o0.x, bb.y + o0.y, bb.z + o0.z, bb.w + o0.w);
                a1 = make_float4(bb.x + o1.x, bb.y + o1.y, bb.z + o1.z, bb.w + o1.w);
                a2 = make_float4(bb.x + o2.x, bb.y + o2.y, bb.z + o2.z, bb.w + o2.w);
                a3 = make_float4(bb.x + o3.x, bb.y + o3.y, bb.z + o3.z, bb.w + o3.w);
            }
            for (int k = 0; k < H; k += 4) {
                const float4 w0 = *reinterpret_cast<const float4*>(&Wh[(size_t)(k + 0) * G + cw]);
                const float4 w1 = *reinterpret_cast<const float4*>(&Wh[(size_t)(k + 1) * G + cw]);
                const float4 w2 = *reinterpret_cast<const float4*>(&Wh[(size_t)(k + 2) * G + cw]);
                const float4 w3 = *reinterpret_cast<const float4*>(&Wh[(size_t)(k + 3) * G + cw]);
                const float4 x0 = *reinterpret_cast<const float4*>(&h_s[0][k]);
                const float4 x1 = *reinterpret_cast<const float4*>(&h_s[1][k]);
                const float4 x2 = *reinterpret_cast<const float4*>(&h_s[2][k]);
                const float4 x3 = *reinterpret_cast<const float4*>(&h_s[3][k]);
#define ACC4(A, X)                                                              \
    A.x = fmaf(X.x, w0.x, fmaf(X.y, w1.x, fmaf(X.z, w2.x, fmaf(X.w, w3.x, A.x)))); \
    A.y = fmaf(X.x, w0.y, fmaf(X.y, w1.y, fmaf(X.z, w2.y, fmaf(X.w, w3.y, A.y)))); \
    A.z = fmaf(X.x, w0.z, fmaf(X.y, w1.z, fmaf(X.z, w2.z, fmaf(X.w, w3.z, A.z)))); \
    A.w = fmaf(X.x, w0.w, fmaf(X.y, w1.w, fmaf(X.z, w2.w, fmaf(X.w, w3.w, A.w))))
                ACC4(a0, x0);
                ACC4(a1, x1);
                ACC4(a2, x2);
                ACC4(a3, x3);
#undef ACC4
            }
            *reinterpret_cast<float4*>(&gates[0][cw]) = a0;
            *reinterpret_cast<float4*>(&gates[1][cw]) = a1;
            *reinterpret_cast<float4*>(&gates[2][cw]) = a2;
            *reinterpret_cast<float4*>(&gates[3][cw]) = a3;
        }
        __syncthreads();

        // ---------------- phase2: gates += ctx @ Wx (all 8 waves) ----------
        {
            const int cw = wv * 128 + lane * 2;  // 2 cols per lane
            float2 a0 = *reinterpret_cast<float2*>(&gates[0][cw]);
            float2 a1 = *reinterpret_cast<float2*>(&gates[1][cw]);
            float2 a2 = *reinterpret_cast<float2*>(&gates[2][cw]);
            float2 a3 = *reinterpret_cast<float2*>(&gates[3][cw]);
            for (int k = 0; k < D; k += 4) {
                const float2 w0 = *reinterpret_cast<const float2*>(&Wx[(size_t)(k + 0) * G + cw]);
                const float2 w1 = *reinterpret_cast<const float2*>(&Wx[(size_t)(k + 1) * G + cw]);
                const float2 w2 = *reinterpret_cast<const float2*>(&Wx[(size_t)(k + 2) * G + cw]);
                const float2 w3 = *reinterpret_cast<const float2*>(&Wx[(size_t)(k + 3) * G + cw]);
                const float4 x0 = *reinterpret_cast<const float4*>(&ctx_s[0][k]);
                const float4 x1 = *reinterpret_cast<const float4*>(&ctx_s[1][k]);
                const float4 x2 = *reinterpret_cast<const float4*>(&ctx_s[2][k]);
                const float4 x3 = *reinterpret_cast<const float4*>(&ctx_s[3][k]);
#define ACC2(A, X)                                                              \
    A.x = fmaf(X.x, w0.x, fmaf(X.y, w1.x, fmaf(X.z, w2.x, fmaf(X.w, w3.x, A.x)))); \
    A.y = fmaf(X.x, w0.y, fmaf(X.y, w1.y, fmaf(X.z, w2.y, fmaf(X.w, w3.y, A.y))))
                ACC2(a0, x0);
                ACC2(a1, x1);
                ACC2(a2, x2);
                ACC2(a3, x3);
#undef ACC2
            }
            *reinterpret_cast<float2*>(&gates[0][cw]) = a0;
            *reinterpret_cast<float2*>(&gates[1][cw]) = a1;
            *reinterpret_cast<float2*>(&gates[2][cw]) = a2;
            *reinterpret_cast<float2*>(&gates[3][cw]) = a3;
        }
        __syncthreads();

        // ---------------- phase3a: pointwise LSTM cell ----------------
#pragma unroll
        for (int pp = 0; pp < 2; ++pp) {
            const int r = (tid >> 8) + pp * 2;
            const int j = tid & 255;
            const float gi = gates[r][j];
            const float gf = gates[r][256 + j];
            const float gc = gates[r][512 + j];
            const float go = gates[r][768 + j];
            const float cv = fsig(gf) * c_s[r][j] + fsig(gi) * ftanh(gc);
            c_s[r][j] = cv;
            const float hvv = fsig(go) * ftanh(cv);
            h_s[r][j] = hvv;
            hiddens[((size_t)(row0 + r) * NS + t) * H + j] = hvv;
        }
        __syncthreads();

        // ---------------- phase3b: hp = h @ Wh2h + bh2h ----------------
        {
            const int j = tid & 255;
            const int rb = (tid >> 8) * 2;  // rows rb, rb+1
            float acc0 = bh2h[j];
            float acc1 = acc0;
            for (int k = 0; k < H; k += 4) {
                const float w0 = Wh2h[(k + 0) * H + j];
                const float w1 = Wh2h[(k + 1) * H + j];
                const float w2 = Wh2h[(k + 2) * H + j];
                const float w3 = Wh2h[(k + 3) * H + j];
                const float4 xa = *reinterpret_cast<const float4*>(&h_s[rb][k]);
                const float4 xb = *reinterpret_cast<const float4*>(&h_s[rb + 1][k]);
                acc0 = fmaf(xa.x, w0, fmaf(xa.y, w1, fmaf(xa.z, w2, fmaf(xa.w, w3, acc0))));
                acc1 = fmaf(xb.x, w0, fmaf(xb.y, w1, fmaf(xb.z, w2, fmaf(xb.w, w3, acc1))));
            }
            hp_s[rb][j] = acc0;
            hp_s[rb + 1][j] = acc1;
        }
        __syncthreads();
    }
}

// ---------------------------------------------------------------------------
// probs[bt][cls] = hiddens[bt][:] @ Wg + bg
__global__ __launch_bounds__(192) void gen_kernel(
        const float* __restrict__ hiddens, const float* __restrict__ Wg,
        const float* __restrict__ bg, float* __restrict__ out) {
    const int row0 = blockIdx.x * 16 + (threadIdx.x / 96) * 8;
    const int cc = threadIdx.x % 96;
    float acc[8];
    const float bias = bg[cc];
#pragma unroll
    for (int r = 0; r < 8; ++r) acc[r] = bias;
    for (int k = 0; k < H; k += 4) {
        const float w0 = Wg[(k + 0) * C + cc];
        const float w1 = Wg[(k + 1) * C + cc];
        const float w2 = Wg[(k + 2) * C + cc];
        const float w3 = Wg[(k + 3) * C + cc];
#pragma unroll
        for (int r = 0; r < 8; ++r) {
            const float4 x = *reinterpret_cast<const float4*>(
                &hiddens[(size_t)(row0 + r) * H + k]);
            acc[r] = fmaf(x.x, w0, acc[r]);
            acc[r] = fmaf(x.y, w1, acc[r]);
            acc[r] = fmaf(x.z, w2, acc[r]);
            acc[r] = fmaf(x.w, w3, acc[r]);
        }
    }
#pragma unroll
    for (int r = 0; r < 8; ++r) out[(size_t)(row0 + r) * C + cc] = acc[r];
}

// ---------------------------------------------------------------------------
extern "C" void kernel_launch(void* const* d_in, const int* in_sizes, int n_in,
                              void* d_out, int out_size, void* d_ws, size_t ws_size,
                              hipStream_t stream) {
    const float* batch_H = (const float*)d_in[0];
    const int*   text    = (const int*)d_in[1];
    // d_in[2] = batch_max_length (scalar) -> NS hardcoded (out_size/B/C = 26)
    const float* Wi2h    = (const float*)d_in[3];
    const float* Wh2h    = (const float*)d_in[4];
    const float* bh2h    = (const float*)d_in[5];
    const float* w_score = (const float*)d_in[6];
    const float* Wx      = (const float*)d_in[7];
    const float* Wh      = (const float*)d_in[8];
    const float* b_lstm  = (const float*)d_in[9];
    const float* Wg      = (const float*)d_in[10];
    const float* bg      = (const float*)d_in[11];
    float* out = (float*)d_out;

    // workspace (floats): proj | hiddens  (~92 MB)
    float* ws      = (float*)d_ws;
    float* proj    = ws;                          // B*T*H
    float* hiddens = proj + (size_t)B * T * H;    // B*NS*H

    proj_kernel<<<B * T / 32, 256, 0, stream>>>(batch_H, Wi2h, proj);
    decoder_kernel<<<B / 4, 512, 0, stream>>>(proj, batch_H, text, Wx, Wh, b_lstm,
                                              Wh2h, bh2h, w_score, hiddens);
    gen_kernel<<<B * NS / 16, 192, 0, stream>>>(hiddens, Wg, bg, out);
}

// Round 7
// 1406.355 us; speedup vs baseline: 2.2094x; 1.0502x over previous
//
#include <hip/hip_runtime.h>
#include <hip/hip_bf16.h>

// B=1024, T=64, D=256, H=256, C=96, num_steps = batch_max_length+1 = 26.
constexpr int B  = 1024;
constexpr int T  = 64;
constexpr int D  = 256;
constexpr int H  = 256;
constexpr int C  = 96;
constexpr int NS = 26;
constexpr int G  = 4 * H;    // 1024 gate columns (i,f,g,o)

__device__ __forceinline__ float fsig(float x) {
    return __builtin_amdgcn_rcpf(1.0f + __expf(-x));
}
__device__ __forceinline__ float ftanh(float x) {
    // 1 - 2/(e^{2x}+1); exp overflow -> rcp(inf)=0 -> 1; underflow -> -1
    float e = __expf(2.0f * x);
    return fmaf(-2.0f, __builtin_amdgcn_rcpf(e + 1.0f), 1.0f);
}
__device__ __forceinline__ float bf_lo(unsigned int p) {
    union { unsigned int i; float f; } v;
    v.i = p << 16;
    return v.f;
}
__device__ __forceinline__ float bf_hi(unsigned int p) {
    union { unsigned int i; float f; } v;
    v.i = p & 0xFFFF0000u;
    return v.f;
}
__device__ __forceinline__ unsigned short f2bf(float f) {
    __hip_bfloat16 h = __float2bfloat16(f);  // RNE
    return *reinterpret_cast<unsigned short*>(&h);
}

// ---------------------------------------------------------------------------
// batch_H (fp32) -> bf16 copy, one-time. 4 elems/thread, exact grid.
__global__ __launch_bounds__(256) void cvt_kernel(
        const float* __restrict__ in, ushort* __restrict__ out) {
    const int i = blockIdx.x * 256 + threadIdx.x;
    const float4 v = reinterpret_cast<const float4*>(in)[i];
    ushort4 o;
    o.x = f2bf(v.x); o.y = f2bf(v.y); o.z = f2bf(v.z); o.w = f2bf(v.w);
    reinterpret_cast<ushort4*>(out)[i] = o;
}

// ---------------------------------------------------------------------------
// proj = batch_H @ Wi2h, stored BF16 in t-interleaved layout:
//   proj[b*H*T + (h/8)*T*8 + t*8 + (h%8)]
// so the decoder's lane=t score loop reads contiguous 16B/lane (1KB/wave).
__global__ __launch_bounds__(256) void proj_kernel(
        const float* __restrict__ bH, const float* __restrict__ Wi2h,
        ushort* __restrict__ proj) {
    __shared__ float xs[32 * 256];
    const int row0 = blockIdx.x * 32;   // 32 (b,t) rows; 32|row0 -> same b
    const int tid = threadIdx.x;

    const float4* src = reinterpret_cast<const float4*>(bH + (size_t)row0 * D);
    float4* dst = reinterpret_cast<float4*>(xs);
#pragma unroll
    for (int i = 0; i < 8; ++i) dst[tid + 256 * i] = src[tid + 256 * i];
    __syncthreads();

    const int wv = tid >> 6, lane = tid & 63;
    const int r0 = wv * 8;
    const int c0 = lane * 4;
    float4 acc[8];
#pragma unroll
    for (int r = 0; r < 8; ++r) acc[r] = make_float4(0.f, 0.f, 0.f, 0.f);

    for (int k = 0; k < D; k += 4) {
        const float4 w0 = *reinterpret_cast<const float4*>(&Wi2h[(k + 0) * H + c0]);
        const float4 w1 = *reinterpret_cast<const float4*>(&Wi2h[(k + 1) * H + c0]);
        const float4 w2 = *reinterpret_cast<const float4*>(&Wi2h[(k + 2) * H + c0]);
        const float4 w3 = *reinterpret_cast<const float4*>(&Wi2h[(k + 3) * H + c0]);
#pragma unroll
        for (int r = 0; r < 8; ++r) {
            const float4 x = *reinterpret_cast<const float4*>(&xs[(r0 + r) * 256 + k]);
            acc[r].x = fmaf(x.x, w0.x, fmaf(x.y, w1.x, fmaf(x.z, w2.x, fmaf(x.w, w3.x, acc[r].x))));
            acc[r].y = fmaf(x.x, w0.y, fmaf(x.y, w1.y, fmaf(x.z, w2.y, fmaf(x.w, w3.y, acc[r].y))));
            acc[r].z = fmaf(x.x, w0.z, fmaf(x.y, w1.z, fmaf(x.z, w2.z, fmaf(x.w, w3.z, acc[r].z))));
            acc[r].w = fmaf(x.x, w0.w, fmaf(x.y, w1.w, fmaf(x.z, w2.w, fmaf(x.w, w3.w, acc[r].w))));
        }
    }
#pragma unroll
    for (int r = 0; r < 8; ++r) {
        const int brow = row0 + r0 + r;          // global (b,t) row
        const int bb = brow >> 6, tt = brow & 63;
        ushort4 o;
        o.x = f2bf(acc[r].x); o.y = f2bf(acc[r].y);
        o.z = f2bf(acc[r].z); o.w = f2bf(acc[r].w);
        // c0%8 is 0 or 4 -> ushort4 stays inside one 8-elem group
        *reinterpret_cast<ushort4*>(
            &proj[(size_t)bb * H * T + (c0 >> 3) * (T * 8) + tt * 8 + (c0 & 7)]) = o;
    }
}

// ---------------------------------------------------------------------------
// Persistent decoder: 256 blocks x 512 thr (8 waves), 4 rows/block, 26 steps.
// Per step (4 barriers):
//   S1: waves 0-3: scores (lane=t, coalesced proj stream, no per-t shfl) ->
//       softmax (in-wave) -> context (lane=d, bf16 bH stream)   [same-wave deps]
//       waves 4-7: gates = bias + onehot + h@Wh (L2 weight stream)
//   S2: all 8 waves: gates += ctx@Wx
//   S3: pointwise LSTM -> h,c,hiddens
//   S4: hp = h@Wh2h + bh2h
__global__ __launch_bounds__(512, 2) void decoder_kernel(
        const ushort* __restrict__ proj, const ushort* __restrict__ bHb,
        const int* __restrict__ text, const float* __restrict__ Wx,
        const float* __restrict__ Wh, const float* __restrict__ b_lstm,
        const float* __restrict__ Wh2h, const float* __restrict__ bh2h,
        const float* __restrict__ w_score, float* __restrict__ hiddens) {
    __shared__ float hp_s[4][256];
    __shared__ float h_s[4][256];
    __shared__ float c_s[4][256];
    __shared__ float ctx_s[4][256];
    __shared__ float gates[4][1024];
    __shared__ float alpha_s[4][64];
    __shared__ float ws_s[256];

    const int row0 = blockIdx.x * 4;
    const int tid = threadIdx.x;
    const int wv = tid >> 6, lane = tid & 63;

    for (int i = tid; i < 1024; i += 512) {
        const int r = i >> 8, j = i & 255;
        h_s[r][j] = 0.0f;
        c_s[r][j] = 0.0f;
        hp_s[r][j] = bh2h[j];
    }
    if (tid < 256) ws_s[tid] = w_score[tid];
    __syncthreads();

    for (int t = 0; t < NS; ++t) {
        if (wv < 4) {
            const int r = wv;
            // ---- scores: lane = timestep; proj in [b][h/8][t][h%8] layout ----
            const ushort* pb = proj + (size_t)(row0 + r) * H * T + lane * 8;
            float e = 0.0f;
#pragma unroll 4
            for (int h = 0; h < H; h += 8) {
                const uint4 pv = *reinterpret_cast<const uint4*>(pb + (h >> 3) * (T * 8));
                const float4 hp0 = *reinterpret_cast<const float4*>(&hp_s[r][h]);
                const float4 hp1 = *reinterpret_cast<const float4*>(&hp_s[r][h + 4]);
                const float4 w0 = *reinterpret_cast<const float4*>(&ws_s[h]);
                const float4 w1 = *reinterpret_cast<const float4*>(&ws_s[h + 4]);
                e += ftanh(bf_lo(pv.x) + hp0.x) * w0.x;
                e += ftanh(bf_hi(pv.x) + hp0.y) * w0.y;
                e += ftanh(bf_lo(pv.y) + hp0.z) * w0.z;
                e += ftanh(bf_hi(pv.y) + hp0.w) * w0.w;
                e += ftanh(bf_lo(pv.z) + hp1.x) * w1.x;
                e += ftanh(bf_hi(pv.z) + hp1.y) * w1.y;
                e += ftanh(bf_lo(pv.w) + hp1.z) * w1.z;
                e += ftanh(bf_hi(pv.w) + hp1.w) * w1.w;
            }
            // ---- softmax across 64 lanes (= 64 timesteps), in-wave ----
            {
                float m = e;
#pragma unroll
                for (int off = 32; off > 0; off >>= 1) m = fmaxf(m, __shfl_xor(m, off));
                const float p = __expf(e - m);
                float sum = p;
#pragma unroll
                for (int off = 32; off > 0; off >>= 1) sum += __shfl_xor(sum, off);
                alpha_s[r][lane] = p * __builtin_amdgcn_rcpf(sum);
            }
            // ---- context: lane = d-slot, stream bf16 bH over t (same-wave) ----
            {
                const ushort* xb = bHb + (size_t)(row0 + r) * T * D + lane * 4;
                float4 cacc = make_float4(0.f, 0.f, 0.f, 0.f);
#pragma unroll 8
                for (int tt = 0; tt < T; ++tt) {
                    const ushort4 x4 = *reinterpret_cast<const ushort4*>(xb + tt * D);
                    const float av = alpha_s[r][tt];
                    cacc.x = fmaf(av, bf_lo((unsigned)x4.x), cacc.x);
                    cacc.y = fmaf(av, bf_lo((unsigned)x4.y), cacc.y);
                    cacc.z = fmaf(av, bf_lo((unsigned)x4.z), cacc.z);
                    cacc.w = fmaf(av, bf_lo((unsigned)x4.w), cacc.w);
                }
                *reinterpret_cast<float4*>(&ctx_s[r][lane * 4]) = cacc;
            }
        } else {
            // ---- gates partial: bias + onehot + h@Wh (wave owns 256 cols) ----
            const int cw = (wv - 4) * 256 + lane * 4;
            float4 a0, a1, a2, a3;
            {
                const float4 bb = *reinterpret_cast<const float4*>(&b_lstm[cw]);
                const int ch0 = text[(row0 + 0) * NS + t];
                const int ch1 = text[(row0 + 1) * NS + t];
                const int ch2 = text[(row0 + 2) * NS + t];
                const int ch3 = text[(row0 + 3) * NS + t];
                const float4 o0 = *reinterpret_cast<const float4*>(&Wx[(size_t)(D + ch0) * G + cw]);
                const float4 o1 = *reinterpret_cast<const float4*>(&Wx[(size_t)(D + ch1) * G + cw]);
                const float4 o2 = *reinterpret_cast<const float4*>(&Wx[(size_t)(D + ch2) * G + cw]);
                const float4 o3 = *reinterpret_cast<const float4*>(&Wx[(size_t)(D + ch3) * G + cw]);
                a0 = make_float4(bb.x + o0.x, bb.y + o0.y, bb.z + o0.z, bb.w + o0.w);
                a1 = make_float4(bb.x + o1.x, bb.y + o1.y, bb.z + o1.z, bb.w + o1.w);
                a2 = make_float4(bb.x + o2.x, bb.y + o2.y, bb.z + o2.z, bb.w + o2.w);
                a3 = make_float4(bb.x + o3.x, bb.y + o3.y, bb.z + o3.z, bb.w + o3.w);
            }
            for (int k = 0; k < H; k += 4) {
                const float4 w0 = *reinterpret_cast<const float4*>(&Wh[(size_t)(k + 0) * G + cw]);
                const float4 w1 = *reinterpret_cast<const float4*>(&Wh[(size_t)(k + 1) * G + cw]);
                const float4 w2 = *reinterpret_cast<const float4*>(&Wh[(size_t)(k + 2) * G + cw]);
                const float4 w3 = *reinterpret_cast<const float4*>(&Wh[(size_t)(k + 3) * G + cw]);
                const float4 x0 = *reinterpret_cast<const float4*>(&h_s[0][k]);
                const float4 x1 = *reinterpret_cast<const float4*>(&h_s[1][k]);
                const float4 x2 = *reinterpret_cast<const float4*>(&h_s[2][k]);
                const float4 x3 = *reinterpret_cast<const float4*>(&h_s[3][k]);
#define ACC4(A, X)                                                              \
    A.x = fmaf(X.x, w0.x, fmaf(X.y, w1.x, fmaf(X.z, w2.x, fmaf(X.w, w3.x, A.x)))); \
    A.y = fmaf(X.x, w0.y, fmaf(X.y, w1.y, fmaf(X.z, w2.y, fmaf(X.w, w3.y, A.y)))); \
    A.z = fmaf(X.x, w0.z, fmaf(X.y, w1.z, fmaf(X.z, w2.z, fmaf(X.w, w3.z, A.z)))); \
    A.w = fmaf(X.x, w0.w, fmaf(X.y, w1.w, fmaf(X.z, w2.w, fmaf(X.w, w3.w, A.w))))
                ACC4(a0, x0);
                ACC4(a1, x1);
                ACC4(a2, x2);
                ACC4(a3, x3);
#undef ACC4
            }
            *reinterpret_cast<float4*>(&gates[0][cw]) = a0;
            *reinterpret_cast<float4*>(&gates[1][cw]) = a1;
            *reinterpret_cast<float4*>(&gates[2][cw]) = a2;
            *reinterpret_cast<float4*>(&gates[3][cw]) = a3;
        }
        __syncthreads();

        // ---------------- S2: gates += ctx @ Wx (all 8 waves) ----------
        {
            const int cw = wv * 128 + lane * 2;
            float2 a0 = *reinterpret_cast<float2*>(&gates[0][cw]);
            float2 a1 = *reinterpret_cast<float2*>(&gates[1][cw]);
            float2 a2 = *reinterpret_cast<float2*>(&gates[2][cw]);
            float2 a3 = *reinterpret_cast<float2*>(&gates[3][cw]);
            for (int k = 0; k < D; k += 4) {
                const float2 w0 = *reinterpret_cast<const float2*>(&Wx[(size_t)(k + 0) * G + cw]);
                const float2 w1 = *reinterpret_cast<const float2*>(&Wx[(size_t)(k + 1) * G + cw]);
                const float2 w2 = *reinterpret_cast<const float2*>(&Wx[(size_t)(k + 2) * G + cw]);
                const float2 w3 = *reinterpret_cast<const float2*>(&Wx[(size_t)(k + 3) * G + cw]);
                const float4 x0 = *reinterpret_cast<const float4*>(&ctx_s[0][k]);
                const float4 x1 = *reinterpret_cast<const float4*>(&ctx_s[1][k]);
                const float4 x2 = *reinterpret_cast<const float4*>(&ctx_s[2][k]);
                const float4 x3 = *reinterpret_cast<const float4*>(&ctx_s[3][k]);
#define ACC2(A, X)                                                              \
    A.x = fmaf(X.x, w0.x, fmaf(X.y, w1.x, fmaf(X.z, w2.x, fmaf(X.w, w3.x, A.x)))); \
    A.y = fmaf(X.x, w0.y, fmaf(X.y, w1.y, fmaf(X.z, w2.y, fmaf(X.w, w3.y, A.y))))
                ACC2(a0, x0);
                ACC2(a1, x1);
                ACC2(a2, x2);
                ACC2(a3, x3);
#undef ACC2
            }
            *reinterpret_cast<float2*>(&gates[0][cw]) = a0;
            *reinterpret_cast<float2*>(&gates[1][cw]) = a1;
            *reinterpret_cast<float2*>(&gates[2][cw]) = a2;
            *reinterpret_cast<float2*>(&gates[3][cw]) = a3;
        }
        __syncthreads();

        // ---------------- S3: pointwise LSTM cell ----------------
#pragma unroll
        for (int pp = 0; pp < 2; ++pp) {
            const int r = (tid >> 8) + pp * 2;
            const int j = tid & 255;
            const float gi = gates[r][j];
            const float gf = gates[r][256 + j];
            const float gc = gates[r][512 + j];
            const float go = gates[r][768 + j];
            const float cv = fsig(gf) * c_s[r][j] + fsig(gi) * ftanh(gc);
            c_s[r][j] = cv;
            const float hvv = fsig(go) * ftanh(cv);
            h_s[r][j] = hvv;
            hiddens[((size_t)(row0 + r) * NS + t) * H + j] = hvv;
        }
        __syncthreads();

        // ---------------- S4: hp = h @ Wh2h + bh2h ----------------
        {
            const int j = tid & 255;
            const int rb = (tid >> 8) * 2;
            float acc0 = bh2h[j];
            float acc1 = acc0;
            for (int k = 0; k < H; k += 4) {
                const float w0 = Wh2h[(k + 0) * H + j];
                const float w1 = Wh2h[(k + 1) * H + j];
                const float w2 = Wh2h[(k + 2) * H + j];
                const float w3 = Wh2h[(k + 3) * H + j];
                const float4 xa = *reinterpret_cast<const float4*>(&h_s[rb][k]);
                const float4 xb = *reinterpret_cast<const float4*>(&h_s[rb + 1][k]);
                acc0 = fmaf(xa.x, w0, fmaf(xa.y, w1, fmaf(xa.z, w2, fmaf(xa.w, w3, acc0))));
                acc1 = fmaf(xb.x, w0, fmaf(xb.y, w1, fmaf(xb.z, w2, fmaf(xb.w, w3, acc1))));
            }
            hp_s[rb][j] = acc0;
            hp_s[rb + 1][j] = acc1;
        }
        __syncthreads();
    }
}

// ---------------------------------------------------------------------------
// probs[bt][cls] = hiddens[bt][:] @ Wg + bg
__global__ __launch_bounds__(192) void gen_kernel(
        const float* __restrict__ hiddens, const float* __restrict__ Wg,
        const float* __restrict__ bg, float* __restrict__ out) {
    const int row0 = blockIdx.x * 16 + (threadIdx.x / 96) * 8;
    const int cc = threadIdx.x % 96;
    float acc[8];
    const float bias = bg[cc];
#pragma unroll
    for (int r = 0; r < 8; ++r) acc[r] = bias;
    for (int k = 0; k < H; k += 4) {
        const float w0 = Wg[(k + 0) * C + cc];
        const float w1 = Wg[(k + 1) * C + cc];
        const float w2 = Wg[(k + 2) * C + cc];
        const float w3 = Wg[(k + 3) * C + cc];
#pragma unroll
        for (int r = 0; r < 8; ++r) {
            const float4 x = *reinterpret_cast<const float4*>(
                &hiddens[(size_t)(row0 + r) * H + k]);
            acc[r] = fmaf(x.x, w0, acc[r]);
            acc[r] = fmaf(x.y, w1, acc[r]);
            acc[r] = fmaf(x.z, w2, acc[r]);
            acc[r] = fmaf(x.w, w3, acc[r]);
        }
    }
#pragma unroll
    for (int r = 0; r < 8; ++r) out[(size_t)(row0 + r) * C + cc] = acc[r];
}

// ---------------------------------------------------------------------------
extern "C" void kernel_launch(void* const* d_in, const int* in_sizes, int n_in,
                              void* d_out, int out_size, void* d_ws, size_t ws_size,
                              hipStream_t stream) {
    const float* batch_H = (const float*)d_in[0];
    const int*   text    = (const int*)d_in[1];
    // d_in[2] = batch_max_length (scalar) -> NS hardcoded (out_size/B/C = 26)
    const float* Wi2h    = (const float*)d_in[3];
    const float* Wh2h    = (const float*)d_in[4];
    const float* bh2h    = (const float*)d_in[5];
    const float* w_score = (const float*)d_in[6];
    const float* Wx      = (const float*)d_in[7];
    const float* Wh      = (const float*)d_in[8];
    const float* b_lstm  = (const float*)d_in[9];
    const float* Wg      = (const float*)d_in[10];
    const float* bg      = (const float*)d_in[11];
    float* out = (float*)d_out;

    // workspace: proj_bf16 (33.5 MB) | bH_bf16 (33.5 MB) | hiddens (27.3 MB)
    char* wsb = (char*)d_ws;
    ushort* proj_bf = (ushort*)wsb;                               // B*T*H (swizzled)
    ushort* bH_bf   = (ushort*)(wsb + (size_t)B * T * H * 2);     // B*T*D
    float*  hiddens = (float*)(wsb + (size_t)B * T * H * 2 * 2);  // B*NS*H

    cvt_kernel<<<B * T * D / 4 / 256, 256, 0, stream>>>(batch_H, bH_bf);
    proj_kernel<<<B * T / 32, 256, 0, stream>>>(batch_H, Wi2h, proj_bf);
    decoder_kernel<<<B / 4, 512, 0, stream>>>(proj_bf, bH_bf, text, Wx, Wh, b_lstm,
                                              Wh2h, bh2h, w_score, hiddens);
    gen_kernel<<<B * NS / 16, 192, 0, stream>>>(hiddens, Wg, bg, out);
}

// Round 9
// 1278.024 us; speedup vs baseline: 2.4313x; 1.1004x over previous
//
#include <hip/hip_runtime.h>
#include <hip/hip_bf16.h>

// B=1024, T=64, D=256, H=256, C=96, num_steps = batch_max_length+1 = 26.
constexpr int B  = 1024;
constexpr int T  = 64;
constexpr int D  = 256;
constexpr int H  = 256;
constexpr int C  = 96;
constexpr int NS = 26;
constexpr int G  = 4 * H;    // 1024 gate columns (i,f,g,o)

__device__ __forceinline__ float fsig(float x) {
    return __builtin_amdgcn_rcpf(1.0f + __expf(-x));
}
__device__ __forceinline__ float ftanh(float x) {
    // 1 - 2/(e^{2x}+1); exp overflow -> rcp(inf)=0 -> 1; underflow -> -1
    float e = __expf(2.0f * x);
    return fmaf(-2.0f, __builtin_amdgcn_rcpf(e + 1.0f), 1.0f);
}
__device__ __forceinline__ float bf_lo(unsigned int p) {
    union { unsigned int i; float f; } v;
    v.i = p << 16;
    return v.f;
}
__device__ __forceinline__ float bf_hi(unsigned int p) {
    union { unsigned int i; float f; } v;
    v.i = p & 0xFFFF0000u;
    return v.f;
}
__device__ __forceinline__ unsigned short f2bf(float f) {
    __hip_bfloat16 h = __float2bfloat16(f);  // RNE
    return *reinterpret_cast<unsigned short*>(&h);
}

// ---------------------------------------------------------------------------
// batch_H (fp32) -> bf16 copy, one-time. 4 elems/thread, exact grid.
__global__ __launch_bounds__(256) void cvt_kernel(
        const float* __restrict__ in, ushort* __restrict__ out) {
    const int i = blockIdx.x * 256 + threadIdx.x;
    const float4 v = reinterpret_cast<const float4*>(in)[i];
    ushort4 o;
    o.x = f2bf(v.x); o.y = f2bf(v.y); o.z = f2bf(v.z); o.w = f2bf(v.w);
    reinterpret_cast<ushort4*>(out)[i] = o;
}

// ---------------------------------------------------------------------------
// Pack W[2*k2+j][col] (fp32, stride G) -> P[(k2*1024 + col)*2 + j] (bf16).
// One 16B lane-load of P then yields 4 cols x 2 k, coalesced across the wave.
__global__ __launch_bounds__(256) void pack_w_kernel(
        const float* __restrict__ W, ushort* __restrict__ P) {
    const int i = blockIdx.x * 256 + threadIdx.x;   // over (rows/2)*1024
    const int k2 = i >> 10, col = i & 1023;
    ushort2 o;
    o.x = f2bf(W[(size_t)(2 * k2) * G + col]);
    o.y = f2bf(W[(size_t)(2 * k2 + 1) * G + col]);
    *reinterpret_cast<ushort2*>(&P[(size_t)i * 2]) = o;
}

// ---------------------------------------------------------------------------
// proj = batch_H @ Wi2h, stored BF16 in t-interleaved layout:
//   proj[b*H*T + (h/8)*T*8 + t*8 + (h%8)]
__global__ __launch_bounds__(256) void proj_kernel(
        const float* __restrict__ bH, const float* __restrict__ Wi2h,
        ushort* __restrict__ proj) {
    __shared__ float xs[32 * 256];
    const int row0 = blockIdx.x * 32;   // 32 (b,t) rows; 32|row0 -> same b
    const int tid = threadIdx.x;

    const float4* src = reinterpret_cast<const float4*>(bH + (size_t)row0 * D);
    float4* dst = reinterpret_cast<float4*>(xs);
#pragma unroll
    for (int i = 0; i < 8; ++i) dst[tid + 256 * i] = src[tid + 256 * i];
    __syncthreads();

    const int wv = tid >> 6, lane = tid & 63;
    const int r0 = wv * 8;
    const int c0 = lane * 4;
    float4 acc[8];
#pragma unroll
    for (int r = 0; r < 8; ++r) acc[r] = make_float4(0.f, 0.f, 0.f, 0.f);

    for (int k = 0; k < D; k += 4) {
        const float4 w0 = *reinterpret_cast<const float4*>(&Wi2h[(k + 0) * H + c0]);
        const float4 w1 = *reinterpret_cast<const float4*>(&Wi2h[(k + 1) * H + c0]);
        const float4 w2 = *reinterpret_cast<const float4*>(&Wi2h[(k + 2) * H + c0]);
        const float4 w3 = *reinterpret_cast<const float4*>(&Wi2h[(k + 3) * H + c0]);
#pragma unroll
        for (int r = 0; r < 8; ++r) {
            const float4 x = *reinterpret_cast<const float4*>(&xs[(r0 + r) * 256 + k]);
            acc[r].x = fmaf(x.x, w0.x, fmaf(x.y, w1.x, fmaf(x.z, w2.x, fmaf(x.w, w3.x, acc[r].x))));
            acc[r].y = fmaf(x.x, w0.y, fmaf(x.y, w1.y, fmaf(x.z, w2.y, fmaf(x.w, w3.y, acc[r].y))));
            acc[r].z = fmaf(x.x, w0.z, fmaf(x.y, w1.z, fmaf(x.z, w2.z, fmaf(x.w, w3.z, acc[r].z))));
            acc[r].w = fmaf(x.x, w0.w, fmaf(x.y, w1.w, fmaf(x.z, w2.w, fmaf(x.w, w3.w, acc[r].w))));
        }
    }
#pragma unroll
    for (int r = 0; r < 8; ++r) {
        const int brow = row0 + r0 + r;          // global (b,t) row
        const int bb = brow >> 6, tt = brow & 63;
        ushort4 o;
        o.x = f2bf(acc[r].x); o.y = f2bf(acc[r].y);
        o.z = f2bf(acc[r].z); o.w = f2bf(acc[r].w);
        *reinterpret_cast<ushort4*>(
            &proj[(size_t)bb * H * T + (c0 >> 3) * (T * 8) + tt * 8 + (c0 & 7)]) = o;
    }
}

// ---------------------------------------------------------------------------
// Persistent decoder: 256 blocks x 512 thr (8 waves), 4 rows/block, 26 steps.
// Per step (4 barriers):
//   S1: waves 0-3: scores (lane=t) -> softmax -> context   [same-wave deps]
//       waves 4-7: gates = bias + onehot + h@WhP (bf16-packed, 8-deep loads)
//   S2: split-K ctx@WxP: waves 0-3 k=0..127 (+= gates), waves 4-7 k=128..255
//       (-> gpart)
//   S3: pointwise LSTM (gates + gpart) -> h,c,hiddens
//   S4: hp = h@Wh2h + bh2h (fp32)
__global__ __launch_bounds__(512, 2) void decoder_kernel(
        const ushort* __restrict__ proj, const ushort* __restrict__ bHb,
        const int* __restrict__ text, const float* __restrict__ Wx,
        const ushort* __restrict__ WhP, const ushort* __restrict__ WxP,
        const float* __restrict__ b_lstm, const float* __restrict__ Wh2h,
        const float* __restrict__ bh2h, const float* __restrict__ w_score,
        float* __restrict__ hiddens) {
    __shared__ float hp_s[4][256];
    __shared__ float h_s[4][256];
    __shared__ float c_s[4][256];
    __shared__ float ctx_s[4][256];
    __shared__ float gates[4][1024];
    __shared__ float gpart[4][1024];
    __shared__ float alpha_s[4][64];
    __shared__ float ws_s[256];

    const int row0 = blockIdx.x * 4;
    const int tid = threadIdx.x;
    const int wv = tid >> 6, lane = tid & 63;

    for (int i = tid; i < 1024; i += 512) {
        const int r = i >> 8, j = i & 255;
        h_s[r][j] = 0.0f;
        c_s[r][j] = 0.0f;
        hp_s[r][j] = bh2h[j];
    }
    if (tid < 256) ws_s[tid] = w_score[tid];
    __syncthreads();

    for (int t = 0; t < NS; ++t) {
        if (wv < 4) {
            const int r = wv;
            // ---- scores: lane = timestep; proj in [b][h/8][t][h%8] layout ----
            const ushort* pb = proj + (size_t)(row0 + r) * H * T + lane * 8;
            float e = 0.0f;
#pragma unroll 8
            for (int h = 0; h < H; h += 8) {
                const uint4 pv = *reinterpret_cast<const uint4*>(pb + (h >> 3) * (T * 8));
                const float4 hp0 = *reinterpret_cast<const float4*>(&hp_s[r][h]);
                const float4 hp1 = *reinterpret_cast<const float4*>(&hp_s[r][h + 4]);
                const float4 w0 = *reinterpret_cast<const float4*>(&ws_s[h]);
                const float4 w1 = *reinterpret_cast<const float4*>(&ws_s[h + 4]);
                e += ftanh(bf_lo(pv.x) + hp0.x) * w0.x;
                e += ftanh(bf_hi(pv.x) + hp0.y) * w0.y;
                e += ftanh(bf_lo(pv.y) + hp0.z) * w0.z;
                e += ftanh(bf_hi(pv.y) + hp0.w) * w0.w;
                e += ftanh(bf_lo(pv.z) + hp1.x) * w1.x;
                e += ftanh(bf_hi(pv.z) + hp1.y) * w1.y;
                e += ftanh(bf_lo(pv.w) + hp1.z) * w1.z;
                e += ftanh(bf_hi(pv.w) + hp1.w) * w1.w;
            }
            // ---- softmax across 64 lanes (= 64 timesteps), in-wave ----
            {
                float m = e;
#pragma unroll
                for (int off = 32; off > 0; off >>= 1) m = fmaxf(m, __shfl_xor(m, off));
                const float p = __expf(e - m);
                float sum = p;
#pragma unroll
                for (int off = 32; off > 0; off >>= 1) sum += __shfl_xor(sum, off);
                alpha_s[r][lane] = p * __builtin_amdgcn_rcpf(sum);
            }
            // ---- context: lane = d-slot, stream bf16 bH over t (same-wave) ----
            {
                const ushort* xb = bHb + (size_t)(row0 + r) * T * D + lane * 4;
                float4 cacc = make_float4(0.f, 0.f, 0.f, 0.f);
#pragma unroll 8
                for (int tt = 0; tt < T; ++tt) {
                    const ushort4 x4 = *reinterpret_cast<const ushort4*>(xb + tt * D);
                    const float av = alpha_s[r][tt];
                    cacc.x = fmaf(av, bf_lo((unsigned)x4.x), cacc.x);
                    cacc.y = fmaf(av, bf_lo((unsigned)x4.y), cacc.y);
                    cacc.z = fmaf(av, bf_lo((unsigned)x4.z), cacc.z);
                    cacc.w = fmaf(av, bf_lo((unsigned)x4.w), cacc.w);
                }
                *reinterpret_cast<float4*>(&ctx_s[r][lane * 4]) = cacc;
            }
        } else {
            // ---- gates: bias + onehot + h@WhP (wave owns 256 cols) ----
            const int cw = (wv - 4) * 256 + lane * 4;
            float4 a0, a1, a2, a3;
            {
                const float4 bb = *reinterpret_cast<const float4*>(&b_lstm[cw]);
                const int ch0 = text[(row0 + 0) * NS + t];
                const int ch1 = text[(row0 + 1) * NS + t];
                const int ch2 = text[(row0 + 2) * NS + t];
                const int ch3 = text[(row0 + 3) * NS + t];
                const float4 o0 = *reinterpret_cast<const float4*>(&Wx[(size_t)(D + ch0) * G + cw]);
                const float4 o1 = *reinterpret_cast<const float4*>(&Wx[(size_t)(D + ch1) * G + cw]);
                const float4 o2 = *reinterpret_cast<const float4*>(&Wx[(size_t)(D + ch2) * G + cw]);
                const float4 o3 = *reinterpret_cast<const float4*>(&Wx[(size_t)(D + ch3) * G + cw]);
                a0 = make_float4(bb.x + o0.x, bb.y + o0.y, bb.z + o0.z, bb.w + o0.w);
                a1 = make_float4(bb.x + o1.x, bb.y + o1.y, bb.z + o1.z, bb.w + o1.w);
                a2 = make_float4(bb.x + o2.x, bb.y + o2.y, bb.z + o2.z, bb.w + o2.w);
                a3 = make_float4(bb.x + o3.x, bb.y + o3.y, bb.z + o3.z, bb.w + o3.w);
            }
            const ushort* wp = WhP + (size_t)cw * 2;
            for (int kc = 0; kc < 128; kc += 8) {   // k-pairs, 8-deep load chunks
                uint4 pv[8];
#pragma unroll
                for (int u = 0; u < 8; ++u)
                    pv[u] = *reinterpret_cast<const uint4*>(wp + (size_t)(kc + u) * 2048);
#pragma unroll
                for (int u = 0; u < 8; ++u) {
                    const int k0 = (kc + u) * 2;
                    const float2 x0 = *reinterpret_cast<const float2*>(&h_s[0][k0]);
                    const float2 x1 = *reinterpret_cast<const float2*>(&h_s[1][k0]);
                    const float2 x2 = *reinterpret_cast<const float2*>(&h_s[2][k0]);
                    const float2 x3 = *reinterpret_cast<const float2*>(&h_s[3][k0]);
                    const float wl0 = bf_lo(pv[u].x), whh0 = bf_hi(pv[u].x);
                    const float wl1 = bf_lo(pv[u].y), whh1 = bf_hi(pv[u].y);
                    const float wl2 = bf_lo(pv[u].z), whh2 = bf_hi(pv[u].z);
                    const float wl3 = bf_lo(pv[u].w), whh3 = bf_hi(pv[u].w);
#define GACC(A, X)                                      \
    A.x = fmaf(X.x, wl0, fmaf(X.y, whh0, A.x));         \
    A.y = fmaf(X.x, wl1, fmaf(X.y, whh1, A.y));         \
    A.z = fmaf(X.x, wl2, fmaf(X.y, whh2, A.z));         \
    A.w = fmaf(X.x, wl3, fmaf(X.y, whh3, A.w));
                    GACC(a0, x0) GACC(a1, x1) GACC(a2, x2) GACC(a3, x3)
#undef GACC
                }
            }
            *reinterpret_cast<float4*>(&gates[0][cw]) = a0;
            *reinterpret_cast<float4*>(&gates[1][cw]) = a1;
            *reinterpret_cast<float4*>(&gates[2][cw]) = a2;
            *reinterpret_cast<float4*>(&gates[3][cw]) = a3;
        }
        __syncthreads();

        // ---- S2: split-K ctx@WxP; waves 0-3 k2=0..63, waves 4-7 k2=64..127 ----
        {
            const int cw2 = (wv & 3) * 256 + lane * 4;
            const int kb = (wv < 4) ? 0 : 64;
            float4 b0 = make_float4(0.f, 0.f, 0.f, 0.f), b1 = b0, b2 = b0, b3 = b0;
            const ushort* wp = WxP + (size_t)cw2 * 2 + (size_t)kb * 2048;
            for (int kc = 0; kc < 64; kc += 8) {
                uint4 pv[8];
#pragma unroll
                for (int u = 0; u < 8; ++u)
                    pv[u] = *reinterpret_cast<const uint4*>(wp + (size_t)(kc + u) * 2048);
#pragma unroll
                for (int u = 0; u < 8; ++u) {
                    const int k0 = (kb + kc + u) * 2;
                    const float2 x0 = *reinterpret_cast<const float2*>(&ctx_s[0][k0]);
                    const float2 x1 = *reinterpret_cast<const float2*>(&ctx_s[1][k0]);
                    const float2 x2 = *reinterpret_cast<const float2*>(&ctx_s[2][k0]);
                    const float2 x3 = *reinterpret_cast<const float2*>(&ctx_s[3][k0]);
                    const float wl0 = bf_lo(pv[u].x), whh0 = bf_hi(pv[u].x);
                    const float wl1 = bf_lo(pv[u].y), whh1 = bf_hi(pv[u].y);
                    const float wl2 = bf_lo(pv[u].z), whh2 = bf_hi(pv[u].z);
                    const float wl3 = bf_lo(pv[u].w), whh3 = bf_hi(pv[u].w);
#define GACC(A, X)                                      \
    A.x = fmaf(X.x, wl0, fmaf(X.y, whh0, A.x));         \
    A.y = fmaf(X.x, wl1, fmaf(X.y, whh1, A.y));         \
    A.z = fmaf(X.x, wl2, fmaf(X.y, whh2, A.z));         \
    A.w = fmaf(X.x, wl3, fmaf(X.y, whh3, A.w));
                    GACC(b0, x0) GACC(b1, x1) GACC(b2, x2) GACC(b3, x3)
#undef GACC
                }
            }
            if (wv < 4) {
#pragma unroll
                for (int r = 0; r < 4; ++r) {
                    const float4 br = (r == 0) ? b0 : (r == 1) ? b1 : (r == 2) ? b2 : b3;
                    float4 g = *reinterpret_cast<float4*>(&gates[r][cw2]);
                    g.x += br.x; g.y += br.y; g.z += br.z; g.w += br.w;
                    *reinterpret_cast<float4*>(&gates[r][cw2]) = g;
                }
            } else {
                *reinterpret_cast<float4*>(&gpart[0][cw2]) = b0;
                *reinterpret_cast<float4*>(&gpart[1][cw2]) = b1;
                *reinterpret_cast<float4*>(&gpart[2][cw2]) = b2;
                *reinterpret_cast<float4*>(&gpart[3][cw2]) = b3;
            }
        }
        __syncthreads();

        // ---------------- S3: pointwise LSTM cell ----------------
#pragma unroll
        for (int pp = 0; pp < 2; ++pp) {
            const int r = (tid >> 8) + pp * 2;
            const int j = tid & 255;
            const float gi = gates[r][j] + gpart[r][j];
            const float gf = gates[r][256 + j] + gpart[r][256 + j];
            const float gc = gates[r][512 + j] + gpart[r][512 + j];
            const float go = gates[r][768 + j] + gpart[r][768 + j];
            const float cv = fsig(gf) * c_s[r][j] + fsig(gi) * ftanh(gc);
            c_s[r][j] = cv;
            const float hvv = fsig(go) * ftanh(cv);
            h_s[r][j] = hvv;
            hiddens[((size_t)(row0 + r) * NS + t) * H + j] = hvv;
        }
        __syncthreads();

        // ---------------- S4: hp = h @ Wh2h + bh2h (fp32) ----------------
        {
            const int j = tid & 255;
            const int rb = (tid >> 8) * 2;
            float acc0 = bh2h[j];
            float acc1 = acc0;
#pragma unroll 4
            for (int k = 0; k < H; k += 4) {
                const float w0 = Wh2h[(k + 0) * H + j];
                const float w1 = Wh2h[(k + 1) * H + j];
                const float w2 = Wh2h[(k + 2) * H + j];
                const float w3 = Wh2h[(k + 3) * H + j];
                const float4 xa = *reinterpret_cast<const float4*>(&h_s[rb][k]);
                const float4 xb = *reinterpret_cast<const float4*>(&h_s[rb + 1][k]);
                acc0 = fmaf(xa.x, w0, fmaf(xa.y, w1, fmaf(xa.z, w2, fmaf(xa.w, w3, acc0))));
                acc1 = fmaf(xb.x, w0, fmaf(xb.y, w1, fmaf(xb.z, w2, fmaf(xb.w, w3, acc1))));
            }
            hp_s[rb][j] = acc0;
            hp_s[rb + 1][j] = acc1;
        }
        __syncthreads();
    }
}

// ---------------------------------------------------------------------------
// probs[bt][cls] = hiddens[bt][:] @ Wg + bg
__global__ __launch_bounds__(192) void gen_kernel(
        const float* __restrict__ hiddens, const float* __restrict__ Wg,
        const float* __restrict__ bg, float* __restrict__ out) {
    const int row0 = blockIdx.x * 16 + (threadIdx.x / 96) * 8;
    const int cc = threadIdx.x % 96;
    float acc[8];
    const float bias = bg[cc];
#pragma unroll
    for (int r = 0; r < 8; ++r) acc[r] = bias;
    for (int k = 0; k < H; k += 4) {
        const float w0 = Wg[(k + 0) * C + cc];
        const float w1 = Wg[(k + 1) * C + cc];
        const float w2 = Wg[(k + 2) * C + cc];
        const float w3 = Wg[(k + 3) * C + cc];
#pragma unroll
        for (int r = 0; r < 8; ++r) {
            const float4 x = *reinterpret_cast<const float4*>(
                &hiddens[(size_t)(row0 + r) * H + k]);
            acc[r] = fmaf(x.x, w0, acc[r]);
            acc[r] = fmaf(x.y, w1, acc[r]);
            acc[r] = fmaf(x.z, w2, acc[r]);
            acc[r] = fmaf(x.w, w3, acc[r]);
        }
    }
#pragma unroll
    for (int r = 0; r < 8; ++r) out[(size_t)(row0 + r) * C + cc] = acc[r];
}

// ---------------------------------------------------------------------------
extern "C" void kernel_launch(void* const* d_in, const int* in_sizes, int n_in,
                              void* d_out, int out_size, void* d_ws, size_t ws_size,
                              hipStream_t stream) {
    const float* batch_H = (const float*)d_in[0];
    const int*   text    = (const int*)d_in[1];
    // d_in[2] = batch_max_length (scalar) -> NS hardcoded (out_size/B/C = 26)
    const float* Wi2h    = (const float*)d_in[3];
    const float* Wh2h    = (const float*)d_in[4];
    const float* bh2h    = (const float*)d_in[5];
    const float* w_score = (const float*)d_in[6];
    const float* Wx      = (const float*)d_in[7];
    const float* Wh      = (const float*)d_in[8];
    const float* b_lstm  = (const float*)d_in[9];
    const float* Wg      = (const float*)d_in[10];
    const float* bg      = (const float*)d_in[11];
    float* out = (float*)d_out;

    // workspace: proj_bf16 33.5MB | bH_bf16 33.5MB | hiddens 27.3MB | WhP 0.5MB | WxP 0.5MB
    char* wsb = (char*)d_ws;
    ushort* proj_bf = (ushort*)wsb;                                   // B*T*H
    ushort* bH_bf   = (ushort*)(wsb + (size_t)B * T * H * 2);         // B*T*D
    float*  hiddens = (float*)(wsb + (size_t)B * T * H * 2 * 2);      // B*NS*H
    ushort* WhP     = (ushort*)(wsb + (size_t)B * T * H * 2 * 2 +
                                (size_t)B * NS * H * 4);              // (H/2)*G*2
    ushort* WxP     = WhP + (size_t)(H / 2) * G * 2;                  // (D/2)*G*2

    cvt_kernel<<<B * T * D / 4 / 256, 256, 0, stream>>>(batch_H, bH_bf);
    pack_w_kernel<<<(H / 2) * G / 256, 256, 0, stream>>>(Wh, WhP);
    pack_w_kernel<<<(D / 2) * G / 256, 256, 0, stream>>>(Wx, WxP);  // rows 0..D-1
    proj_kernel<<<B * T / 32, 256, 0, stream>>>(batch_H, Wi2h, proj_bf);
    decoder_kernel<<<B / 4, 512, 0, stream>>>(proj_bf, bH_bf, text, Wx, WhP, WxP,
                                              b_lstm, Wh2h, bh2h, w_score, hiddens);
    gen_kernel<<<B * NS / 16, 192, 0, stream>>>(hiddens, Wg, bg, out);
}